// Round 5
// baseline (103.412 us; speedup 1.0000x reference)
//
#include <hip/hip_runtime.h>

// LIF recurrence: mem = 0.9*mem + x; spike = (mem >= 1); record; mem -= spike.
// T=20, elementwise-independent. Output: [spikes T*N][mems T*N], fp32.
//
// R5: CALIBRATION ROUND. Four structurally different kernels (R1-R4) all land
// at 90-93 us total; the timed graph contains harness poison fills (~55us for
// the 320MiB ws fill is visible in rocprof; an ~13.5us 80MiB out fill would be
// hidden below top-5). To measure our kernel's true dispatch time, launch the
// identical idempotent kernel TWICE: dur_R5 - dur_R4 = one kernel dispatch.
// Body = R2 variant (fastest so far: simple, NT stores, 512 blocks).
//
// Numerics: forced mul-then-add (__fmul_rn/__fadd_rn), no FMA contraction --
// 1-ulp drift flips the >=1.0 threshold (absmax=1.0 failure mode).

#define TSTEPS 20

typedef float v4f __attribute__((ext_vector_type(4)));

__global__ __launch_bounds__(256) void
TemporalEncoding_57672820850797_kernel(const v4f* __restrict__ x,
                                       float* __restrict__ out, int n4) {
    int i = blockIdx.x * blockDim.x + threadIdx.x;  // float4 index
    if (i >= n4) return;

    const v4f xv = __builtin_nontemporal_load(&x[i]);
    v4f* __restrict__ spikes = reinterpret_cast<v4f*>(out) + i;
    v4f* __restrict__ mems   = reinterpret_cast<v4f*>(out) + (size_t)TSTEPS * n4 + i;

    float m0 = 0.f, m1 = 0.f, m2 = 0.f, m3 = 0.f;

#pragma unroll
    for (int t = 0; t < TSTEPS; ++t) {
        // mem = 0.9*mem + x (separate rounding steps, matches numpy exactly)
        m0 = __fadd_rn(__fmul_rn(0.9f, m0), xv.x);
        m1 = __fadd_rn(__fmul_rn(0.9f, m1), xv.y);
        m2 = __fadd_rn(__fmul_rn(0.9f, m2), xv.z);
        m3 = __fadd_rn(__fmul_rn(0.9f, m3), xv.w);

        float s0 = (m0 >= 1.0f) ? 1.0f : 0.0f;
        float s1 = (m1 >= 1.0f) ? 1.0f : 0.0f;
        float s2 = (m2 >= 1.0f) ? 1.0f : 0.0f;
        float s3 = (m3 >= 1.0f) ? 1.0f : 0.0f;

        v4f sv; sv.x = s0; sv.y = s1; sv.z = s2; sv.w = s3;
        v4f mv; mv.x = m0; mv.y = m1; mv.z = m2; mv.w = m3;
        __builtin_nontemporal_store(sv, spikes);
        __builtin_nontemporal_store(mv, mems);
        spikes += n4;
        mems   += n4;

        m0 -= s0;
        m1 -= s1;
        m2 -= s2;
        m3 -= s3;
    }
}

extern "C" void kernel_launch(void* const* d_in, const int* in_sizes, int n_in,
                              void* d_out, int out_size, void* d_ws, size_t ws_size,
                              hipStream_t stream) {
    const float* x = (const float*)d_in[0];
    float* out = (float*)d_out;
    const int n = in_sizes[0];       // 64*8192 = 524288
    const int n4 = n / 4;            // 131072 float4 lanes
    const int block = 256;
    const int grid = (n4 + block - 1) / block;  // 512 blocks
    // Launch TWICE (idempotent): delta vs R4's single launch = true kernel time.
    TemporalEncoding_57672820850797_kernel<<<grid, block, 0, stream>>>(
        (const v4f*)x, out, n4);
    TemporalEncoding_57672820850797_kernel<<<grid, block, 0, stream>>>(
        (const v4f*)x, out, n4);
}

// Round 6
// 90.418 us; speedup vs baseline: 1.1437x; 1.1437x over previous
//
#include <hip/hip_runtime.h>

// LIF recurrence: mem = 0.9*mem + x; spike = (mem >= 1); record; mem -= spike.
// T=20, elementwise-independent. Output: [spikes T*N][mems T*N], fp32.
//
// R6: FINAL — revert R5's calibration double-launch back to single launch.
// Calibration result (R5 vs R2/R4 delta): one kernel dispatch = ~11-13 us for
// 86 MB of HBM traffic = ~6.4 TB/s, at the measured achievable ceiling (the
// harness's own 320 MiB poison fill sustains 6.2 TB/s on this box). The
// ~90 us reported dur_us is dominated by in-graph harness re-poison fills
// (~77 us), not the kernel. R3 (4x occupancy) and R4 (stream-ordered persistent
// grid) were neutral because the kernel was already roofline-bound.
//
// Numerics: forced mul-then-add (__fmul_rn/__fadd_rn), no FMA contraction --
// 1-ulp drift flips the >=1.0 threshold (absmax=1.0 failure mode).

#define TSTEPS 20

typedef float v4f __attribute__((ext_vector_type(4)));

__global__ __launch_bounds__(256) void
TemporalEncoding_57672820850797_kernel(const v4f* __restrict__ x,
                                       float* __restrict__ out, int n4) {
    int i = blockIdx.x * blockDim.x + threadIdx.x;  // float4 index
    if (i >= n4) return;

    const v4f xv = __builtin_nontemporal_load(&x[i]);
    v4f* __restrict__ spikes = reinterpret_cast<v4f*>(out) + i;
    v4f* __restrict__ mems   = reinterpret_cast<v4f*>(out) + (size_t)TSTEPS * n4 + i;

    float m0 = 0.f, m1 = 0.f, m2 = 0.f, m3 = 0.f;

#pragma unroll
    for (int t = 0; t < TSTEPS; ++t) {
        // mem = 0.9*mem + x (separate rounding steps, matches numpy exactly)
        m0 = __fadd_rn(__fmul_rn(0.9f, m0), xv.x);
        m1 = __fadd_rn(__fmul_rn(0.9f, m1), xv.y);
        m2 = __fadd_rn(__fmul_rn(0.9f, m2), xv.z);
        m3 = __fadd_rn(__fmul_rn(0.9f, m3), xv.w);

        float s0 = (m0 >= 1.0f) ? 1.0f : 0.0f;
        float s1 = (m1 >= 1.0f) ? 1.0f : 0.0f;
        float s2 = (m2 >= 1.0f) ? 1.0f : 0.0f;
        float s3 = (m3 >= 1.0f) ? 1.0f : 0.0f;

        v4f sv; sv.x = s0; sv.y = s1; sv.z = s2; sv.w = s3;
        v4f mv; mv.x = m0; mv.y = m1; mv.z = m2; mv.w = m3;
        __builtin_nontemporal_store(sv, spikes);
        __builtin_nontemporal_store(mv, mems);
        spikes += n4;
        mems   += n4;

        m0 -= s0;
        m1 -= s1;
        m2 -= s2;
        m3 -= s3;
    }
}

extern "C" void kernel_launch(void* const* d_in, const int* in_sizes, int n_in,
                              void* d_out, int out_size, void* d_ws, size_t ws_size,
                              hipStream_t stream) {
    const float* x = (const float*)d_in[0];
    float* out = (float*)d_out;
    const int n = in_sizes[0];       // 64*8192 = 524288
    const int n4 = n / 4;            // 131072 float4 lanes
    const int block = 256;
    const int grid = (n4 + block - 1) / block;  // 512 blocks
    TemporalEncoding_57672820850797_kernel<<<grid, block, 0, stream>>>(
        (const v4f*)x, out, n4);
}